// Round 10
// baseline (492.274 us; speedup 1.0000x reference)
//
#include <hip/hip_runtime.h>
#include <hip/hip_bf16.h>
#include <math.h>

// Problem constants (from reference setup_inputs)
#define B_  64
#define T_  1000
#define D_  512
#define V_  29
#define L_  200
#define S_  401          // 2*L+1
#define VPAD 32          // padded stride for prob rows
#define BLANK_ 28
#define HROWS 500        // half-slice rows (flen >= 500 always)

typedef __attribute__((ext_vector_type(8))) short short8v;   // 8 bf16 (4 VGPRs)
typedef __attribute__((ext_vector_type(4))) float float4v;   // MFMA acc

// f32 -> bf16 bits, round-to-nearest-even (finite inputs)
__device__ __forceinline__ unsigned short f2bf(float f) {
    unsigned int u = __float_as_uint(f);
    return (unsigned short)((u + 0x7FFFu + ((u >> 16) & 1u)) >> 16);
}

// ---------------------------------------------------------------------------
// Kernel 1: head GEMM (Linear D->V) via bf16 MFMA + fused softmax.
// (Unchanged from round 9 — passed, absmax 0.0.)
// ---------------------------------------------------------------------------
__global__ __launch_bounds__(256) void head_mfma_softmax_kernel(
    const float* __restrict__ feat,   // [B][T][D]
    const float* __restrict__ W,      // [D][V]
    const float* __restrict__ bias,   // [V]
    const int*   __restrict__ flen,   // [B]
    float*       __restrict__ p)      // [B][T][VPAD]
{
    __shared__ uint4 bfrag_lds[16 * 2 * 64];   // 32 KB: [kstep][ntile][lane]
    const int tid = threadIdx.x;

    // ---- stage W as bf16 B-fragments (once per block) ----
    for (int f = tid; f < 2048; f += 256) {
        int ks  = f >> 7;
        int rem = f & 127;
        int tl  = rem >> 6;
        int ln  = rem & 63;
        int k0  = ks * 32 + (ln >> 4) * 8;
        int col = tl * 16 + (ln & 15);
        unsigned short h[8];
        #pragma unroll
        for (int j = 0; j < 8; ++j) {
            float wv = (col < V_) ? W[(size_t)(k0 + j) * V_ + col] : 0.f;
            h[j] = f2bf(wv);
        }
        uint4 pk;
        pk.x = h[0] | ((unsigned)h[1] << 16);
        pk.y = h[2] | ((unsigned)h[3] << 16);
        pk.z = h[4] | ((unsigned)h[5] << 16);
        pk.w = h[6] | ((unsigned)h[7] << 16);
        bfrag_lds[f] = pk;
    }
    __syncthreads();

    const int wv  = tid >> 6;        // wave 0..3
    const int l   = tid & 63;
    const int c0  = l & 15;
    const int grp = l >> 4;
    const float bias0 = bias[c0];
    const bool  v1ok  = (c0 + 16) < V_;
    const float bias1 = v1ok ? bias[c0 + 16] : 0.f;

    #pragma unroll
    for (int ti = 0; ti < 2; ++ti) {
        const int tile = (blockIdx.x * 4 + wv) * 2 + ti;  // 0..3999
        const int r0   = tile * 16;
        const int b0 = r0 / T_;
        const bool active = ((r0 - b0 * T_) < flen[b0]) || ((r0 + 15) / T_ != b0);
        if (!active) continue;

        const float* abase = feat + (size_t)(r0 + c0) * D_ + grp * 8;
        float4v acc0 = {0.f, 0.f, 0.f, 0.f};
        float4v acc1 = {0.f, 0.f, 0.f, 0.f};

        #pragma unroll 4
        for (int ks = 0; ks < 16; ++ks) {
            float4 fa = *(const float4*)(abase + ks * 32);
            float4 fb = *(const float4*)(abase + ks * 32 + 4);
            short8v a;
            a[0] = (short)f2bf(fa.x); a[1] = (short)f2bf(fa.y);
            a[2] = (short)f2bf(fa.z); a[3] = (short)f2bf(fa.w);
            a[4] = (short)f2bf(fb.x); a[5] = (short)f2bf(fb.y);
            a[6] = (short)f2bf(fb.z); a[7] = (short)f2bf(fb.w);
            uint4 b0v = bfrag_lds[(ks * 2 + 0) * 64 + l];
            uint4 b1v = bfrag_lds[(ks * 2 + 1) * 64 + l];
            acc0 = __builtin_amdgcn_mfma_f32_16x16x32_bf16(
                       a, __builtin_bit_cast(short8v, b0v), acc0, 0, 0, 0);
            acc1 = __builtin_amdgcn_mfma_f32_16x16x32_bf16(
                       a, __builtin_bit_cast(short8v, b1v), acc1, 0, 0, 0);
        }

        #pragma unroll
        for (int j = 0; j < 4; ++j) {
            float lg0 = acc0[j] + bias0;
            float lg1 = v1ok ? (acc1[j] + bias1) : -1e30f;
            float m = fmaxf(lg0, lg1);
            #pragma unroll
            for (int off = 1; off <= 8; off <<= 1)
                m = fmaxf(m, __shfl_xor(m, off));
            float e0 = __expf(lg0 - m);
            float e1 = v1ok ? __expf(lg1 - m) : 0.f;
            float s = e0 + e1;
            #pragma unroll
            for (int off = 1; off <= 8; off <<= 1)
                s += __shfl_xor(s, off);
            float invs = 1.f / s;
            int r = r0 + grp * 4 + j;
            p[(size_t)r * VPAD + c0]      = e0 * invs;
            p[(size_t)r * VPAD + c0 + 16] = e1 * invs;   // cols 29..31 -> 0
        }
    }
}

// ---------------------------------------------------------------------------
// Kernel 2: CTC alpha recursion, TWO SAMPLES PER BLOCK (b, b+32) with the
// two independent dependent-chains interleaved in one basic block — an
// in-order wave can't overlap a serial chain with itself, but the compiler
// CAN interleave two. Same proven linear-space + per-lane integer pow-2
// scaling math (byte-identical CTC_STEP). LDS holds 500-row half-slices of
// both samples (125 KB); one restage at t=500. flen >= 500, so phase 1 is
// unpredicated; phase 2 freezes per-sample via branchless uniform selects
// (branches would split the BB and kill interleaving).
// ---------------------------------------------------------------------------
__device__ __forceinline__ float wave_shr1_zero(float x) {
    return __int_as_float(__builtin_amdgcn_update_dpp(
        0, __float_as_int(x), 0x138 /*wave_shr:1*/, 0xf, 0xf, true));
}
__device__ __forceinline__ int shr1_self_i(int x) {
    return __builtin_amdgcn_update_dpp(x, x, 0x138 /*wave_shr:1*/, 0xf, 0xf, false);
}

#define TWO60  1.152921504606846976e18f   // 2^60
#define TWOM60 8.673617379884035e-19f     // 2^-60
#define NEGLOG2 (-1.5e9f)                 // log2-domain stand-in for -inf

// one trellis step; act=false freezes (selects keep old r,c). Single BB.
#define CTC_STEP(rr, cc, Q, alw, act) do {                                    \
    int   cp = shr1_self_i(cc);                                               \
    float u1 = wave_shr1_zero(rr[6]);                                         \
    float u2 = wave_shr1_zero(rr[5]);                                         \
    int   cm = (cc > cp) ? cc : cp;                                           \
    int   dc = cc - cm; if (dc < -127) dc = -127;                             \
    int   dp = cp - cm; if (dp < -127) dp = -127;                             \
    float fs = __int_as_float((dc + 127) << 23);                              \
    float fu = __int_as_float((dp + 127) << 23);                              \
    u1 *= fu; u2 *= fu;                                                       \
    float s0 = rr[0]*fs, s1 = rr[1]*fs, s2 = rr[2]*fs, s3 = rr[3]*fs;         \
    float s4 = rr[4]*fs, s5 = rr[5]*fs, s6 = rr[6]*fs;                        \
    float n0 = Q[0] * (s0 + u1 + alw[0] * u2);                                \
    float n1 = Q[1] * (s1 + s0 + alw[1] * u1);                                \
    float n2 = Q[2] * (s2 + s1 + alw[2] * s0);                                \
    float n3 = Q[3] * (s3 + s2 + alw[3] * s1);                                \
    float n4 = Q[4] * (s4 + s3 + alw[4] * s2);                                \
    float n5 = Q[5] * (s5 + s4 + alw[5] * s3);                                \
    float n6 = Q[6] * (s6 + s5 + alw[6] * s4);                                \
    float m  = fmaxf(fmaxf(fmaxf(n0, n1), fmaxf(n2, n3)),                     \
                     fmaxf(fmaxf(n4, n5), n6));                               \
    m = fmaxf(m, TWOM60);                                                     \
    int e   = (__float_as_int(m) >> 23) - 127;  /* floor(log2(m)) */          \
    float sc = __int_as_float((187 - e) << 23); /* 2^(60-e), exact */         \
    rr[0] = (act) ? n0*sc : rr[0];  rr[1] = (act) ? n1*sc : rr[1];            \
    rr[2] = (act) ? n2*sc : rr[2];  rr[3] = (act) ? n3*sc : rr[3];            \
    rr[4] = (act) ? n4*sc : rr[4];  rr[5] = (act) ? n5*sc : rr[5];            \
    rr[6] = (act) ? n6*sc : rr[6];                                            \
    cc = (act) ? (cm + e - 60) : cc;                                          \
} while (0)

#define PREFETCH(Q, base, rowoff, oi) do {                                    \
    int _ba = (rowoff) * VPAD;                                                \
    Q[0]=base[_ba+oi[0]]; Q[1]=base[_ba+oi[1]]; Q[2]=base[_ba+oi[2]];         \
    Q[3]=base[_ba+oi[3]]; Q[4]=base[_ba+oi[4]]; Q[5]=base[_ba+oi[5]];         \
    Q[6]=base[_ba+oi[6]];                                                     \
} while (0)

#define SETUP_TRELLIS(oi, alw, bb) do {                                       \
    _Pragma("unroll")                                                         \
    for (int k = 0; k < 7; ++k) {                                             \
        int s = 7 * lane + k;                                                 \
        int o = 29;              /* invalid state -> zeroed pad column */     \
        float al = 0.f;                                                       \
        if (s < S_) {                                                         \
            if (s & 1) {                                                      \
                int li = (s - 1) >> 1;                                        \
                o = labels[(bb) * L_ + li];                                   \
                if (s >= 3) al = (o != labels[(bb) * L_ + li - 1]) ? 1.f:0.f; \
            } else { o = BLANK_; }                                            \
        }                                                                     \
        oi[k] = o; alw[k] = al;                                               \
    }                                                                         \
} while (0)

__global__ __launch_bounds__(256) void ctc_alpha_lds2_kernel(
    const float* __restrict__ p,      // [B][T][VPAD] probs
    const int*   __restrict__ labels, // [B][L]
    const int*   __restrict__ flen,   // [B]
    const int*   __restrict__ llen,   // [B]
    float*       __restrict__ nll)    // [B]
{
    __shared__ float ldsA[HROWS * VPAD];        // 62.5 KB each
    __shared__ float ldsB[HROWS * VPAD];
    const int bA  = blockIdx.x;
    const int bB  = blockIdx.x + 32;
    const int tid = threadIdx.x;
    const float* pA = p + (size_t)bA * T_ * VPAD;
    const float* pB = p + (size_t)bB * T_ * VPAD;
    const int TbA = flen[bA], TbB = flen[bB];
    const int mTb = (TbA > TbB) ? TbA : TbB;

    // ---- stage phase-1 half-slices: rows [0, 500) of both samples ----
    {
        const float4* sA = (const float4*)pA;
        const float4* sB = (const float4*)pB;
        float4* dA = (float4*)ldsA;
        float4* dB = (float4*)ldsB;
        for (int i = tid; i < HROWS * (VPAD / 4); i += 256) {
            dA[i] = sA[i];
            dB[i] = sB[i];
        }
    }
    __syncthreads();

    int   oiA[7], oiB[7];
    float alwA[7], alwB[7];
    float rA[7], rB[7];
    int   cA = -60, cB = -60;
    float qAA[7], qBA[7], qN1A[7], qN2A[7];
    float qAB[7], qBB[7], qN1B[7], qN2B[7];
    const int lane = tid;

    if (tid < 64) {
        SETUP_TRELLIS(oiA, alwA, bA);
        SETUP_TRELLIS(oiB, alwB, bB);

        // t = 0 init from LDS row 0
        {
            float q0[7];
            PREFETCH(q0, ldsA, 0, oiA);
            #pragma unroll
            for (int k = 0; k < 7; ++k)
                rA[k] = (lane == 0 && k < 2) ? q0[k] * TWO60 : 0.f;
            PREFETCH(q0, ldsB, 0, oiB);
            #pragma unroll
            for (int k = 0; k < 7; ++k)
                rB[k] = (lane == 0 && k < 2) ? q0[k] * TWO60 : 0.f;
        }

        // ---- phase 1: steps t = 1..499, unpredicated (Tb >= 500) ----
        PREFETCH(qAA, ldsA, 1, oiA);  PREFETCH(qAB, ldsB, 1, oiB);
        PREFETCH(qBA, ldsA, 2, oiA);  PREFETCH(qBB, ldsB, 2, oiB);
        int t = 1;
        for (; t + 1 < HROWS; t += 2) {
            int ro1 = t + 2; if (ro1 > HROWS - 1) ro1 = HROWS - 1;
            int ro2 = t + 3; if (ro2 > HROWS - 1) ro2 = HROWS - 1;
            PREFETCH(qN1A, ldsA, ro1, oiA);
            PREFETCH(qN1B, ldsB, ro1, oiB);
            CTC_STEP(rA, cA, qAA, alwA, true);
            CTC_STEP(rB, cB, qAB, alwB, true);
            PREFETCH(qN2A, ldsA, ro2, oiA);
            PREFETCH(qN2B, ldsB, ro2, oiB);
            CTC_STEP(rA, cA, qBA, alwA, true);
            CTC_STEP(rB, cB, qBB, alwB, true);
            #pragma unroll
            for (int k = 0; k < 7; ++k) {
                qAA[k] = qN1A[k]; qBA[k] = qN2A[k];
                qAB[k] = qN1B[k]; qBB[k] = qN2B[k];
            }
        }
        // leftover step t = 499
        CTC_STEP(rA, cA, qAA, alwA, true);
        CTC_STEP(rB, cB, qAB, alwB, true);
    }
    __syncthreads();

    // ---- stage phase-2: rows [500, Tb) of each sample ----
    {
        const float4* sA = (const float4*)(pA + HROWS * VPAD);
        const float4* sB = (const float4*)(pB + HROWS * VPAD);
        float4* dA = (float4*)ldsA;
        float4* dB = (float4*)ldsB;
        const int nA4 = (TbA - HROWS) * (VPAD / 4);   // may be 0
        const int nB4 = (TbB - HROWS) * (VPAD / 4);
        const int n4  = (nA4 > nB4) ? nA4 : nB4;
        for (int i = tid; i < n4; i += 256) {
            if (i < nA4) dA[i] = sA[i];
            if (i < nB4) dB[i] = sB[i];
        }
    }
    __syncthreads();

    if (tid < 64) {
        if (mTb > HROWS) {
            // ---- phase 2: steps t = 500..mTb-1, per-sample freeze ----
            PREFETCH(qAA, ldsA, 0, oiA);  PREFETCH(qAB, ldsB, 0, oiB);
            PREFETCH(qBA, ldsA, 1, oiA);  PREFETCH(qBB, ldsB, 1, oiB);
            int t = HROWS;
            for (; t + 1 < mTb; t += 2) {
                int ro1 = t + 2 - HROWS; if (ro1 > HROWS - 1) ro1 = HROWS - 1;
                int ro2 = t + 3 - HROWS; if (ro2 > HROWS - 1) ro2 = HROWS - 1;
                PREFETCH(qN1A, ldsA, ro1, oiA);
                PREFETCH(qN1B, ldsB, ro1, oiB);
                CTC_STEP(rA, cA, qAA, alwA, (t < TbA));
                CTC_STEP(rB, cB, qAB, alwB, (t < TbB));
                PREFETCH(qN2A, ldsA, ro2, oiA);
                PREFETCH(qN2B, ldsB, ro2, oiB);
                CTC_STEP(rA, cA, qBA, alwA, (t + 1 < TbA));
                CTC_STEP(rB, cB, qBB, alwB, (t + 1 < TbB));
                #pragma unroll
                for (int k = 0; k < 7; ++k) {
                    qAA[k] = qN1A[k]; qBA[k] = qN2A[k];
                    qAB[k] = qN1B[k]; qBB[k] = qN2B[k];
                }
            }
            if (t < mTb) {
                CTC_STEP(rA, cA, qAA, alwA, (t < TbA));
                CTC_STEP(rB, cB, qAB, alwB, (t < TbB));
            }
        }

        // per-state log2(alpha) into reused LDS
        #pragma unroll
        for (int k = 0; k < 7; ++k) {
            float vA = rA[k];
            ldsA[7 * lane + k] = (vA > 0.f) ? ((float)cA + log2f(vA)) : NEGLOG2;
            float vB = rB[k];
            ldsB[7 * lane + k] = (vB > 0.f) ? ((float)cB + log2f(vB)) : NEGLOG2;
        }
    }
    __syncthreads();

    if (tid == 0) {
        #pragma unroll
        for (int which = 0; which < 2; ++which) {
            const float* fin = which ? ldsB : ldsA;
            const int bb = which ? bB : bA;
            const int ll = llen[bb];
            int ib = 2 * ll;                    // <= 400
            float l1 = fin[ib];
            float l2 = (ll > 0) ? fin[ib - 1] : NEGLOG2;
            float mm = fmaxf(l1, l2);
            float s2 = exp2f(l1 - mm) + exp2f(l2 - mm);
            float nl = -0.6931471805599453f * (mm + log2f(s2));
            nll[bb] = (nl < 5e8f) ? nl / fmaxf((float)ll, 1.f) : 0.f;
        }
    }
}

// ---------------------------------------------------------------------------
// Kernel 3: mean over B=64 per-sample losses -> scalar
// ---------------------------------------------------------------------------
__global__ __launch_bounds__(64) void reduce_mean_kernel(
    const float* __restrict__ nll, float* __restrict__ out)
{
    float v = nll[threadIdx.x];
    #pragma unroll
    for (int off = 32; off; off >>= 1) v += __shfl_down(v, off);
    if (threadIdx.x == 0) out[0] = v * (1.0f / (float)B_);
}

// ---------------------------------------------------------------------------
extern "C" void kernel_launch(void* const* d_in, const int* in_sizes, int n_in,
                              void* d_out, int out_size, void* d_ws, size_t ws_size,
                              hipStream_t stream) {
    const float* feat   = (const float*)d_in[0];  // [64,1000,512] f32
    const float* W      = (const float*)d_in[1];  // [512,29] f32
    const float* bias   = (const float*)d_in[2];  // [29] f32
    const int*   labels = (const int*)  d_in[3];  // [64,200] i32
    const int*   flen   = (const int*)  d_in[4];  // [64] i32
    const int*   llen   = (const int*)  d_in[5];  // [64] i32
    float* out = (float*)d_out;

    float* p   = (float*)d_ws;                                    // 8.192 MB
    float* nll = (float*)((char*)d_ws + (size_t)8 * 1024 * 1024); // B floats

    head_mfma_softmax_kernel<<<500, 256, 0, stream>>>(feat, W, bias, flen, p);
    ctc_alpha_lds2_kernel<<<32, 256, 0, stream>>>(p, labels, flen, llen, nll);
    reduce_mean_kernel<<<1, 64, 0, stream>>>(nll, out);
}